// Round 1
// baseline (1730.236 us; speedup 1.0000x reference)
//
#include <hip/hip_runtime.h>
#include <hip/hip_bf16.h>

typedef __bf16 bf16x8 __attribute__((ext_vector_type(8)));
typedef short  short8 __attribute__((ext_vector_type(8)));
typedef float  f32x4  __attribute__((ext_vector_type(4)));

__device__ __forceinline__ short f2bs(float f) {
  return __builtin_bit_cast(short, __float2bfloat16(f));
}

__device__ __forceinline__ bf16x8 ldfrag(const short* p) {
  return *reinterpret_cast<const bf16x8*>(p);
}

// ---------------------------------------------------------------------------
// Weight cast: fp32 -> bf16 (RNE), n divisible by 4
// ---------------------------------------------------------------------------
__global__ __launch_bounds__(256) void cast_f32_bf16(const float* __restrict__ in,
                                                     short* __restrict__ out, int n) {
  int i = (blockIdx.x * 256 + threadIdx.x) * 4;
  if (i < n) {
    float4 v = *reinterpret_cast<const float4*>(in + i);
    out[i + 0] = f2bs(v.x);
    out[i + 1] = f2bs(v.y);
    out[i + 2] = f2bs(v.z);
    out[i + 3] = f2bs(v.w);
  }
}

// ---------------------------------------------------------------------------
// Generic C[M,N] = A[M,K] @ B[N,K]^T (+bias), bf16 MFMA 16x16x32.
// Tile 128x128x32; 256 threads = 4 waves in 2x2, each wave 64x64 (4x4 frags).
// AT: float (cvt in staging) or short (bf16 passthrough).
// OT: short (bf16 store) or float (+optional bias).
// N, K must be multiples of 128 / 32; M guarded.
// ---------------------------------------------------------------------------
template <typename AT, typename OT, bool BIAS>
__global__ __launch_bounds__(256)
void gemm_bt(const AT* __restrict__ A, const short* __restrict__ B,
             const float* __restrict__ bias, OT* __restrict__ C,
             int M, int N, int K) {
  __shared__ short As[128][40];  // stride 40 shorts (80B): 2-way bank alias = free
  __shared__ short Bs[128][40];

  const int tid  = threadIdx.x;
  const int wave = tid >> 6, lane = tid & 63;
  const int quad = lane >> 4, l16 = lane & 15;
  const int wy = wave >> 1, wx = wave & 1;
  const int row0 = blockIdx.y * 128, col0 = blockIdx.x * 128;

  const int sr = tid >> 2;         // staging row 0..63 (two passes)
  const int sc = (tid & 3) * 8;    // staging col 0,8,16,24

  f32x4 acc[4][4] = {};

  for (int k0 = 0; k0 < K; k0 += 32) {
    for (int p = 0; p < 128; p += 64) {
      const int r  = sr + p;
      const int gm = row0 + r;
      short8 va = {0, 0, 0, 0, 0, 0, 0, 0};
      if (gm < M) {
        if constexpr (sizeof(AT) == 4) {  // fp32 -> bf16 inline
          const float* ap = (const float*)A + (size_t)gm * K + k0 + sc;
          float4 x = *reinterpret_cast<const float4*>(ap);
          float4 y = *reinterpret_cast<const float4*>(ap + 4);
          va[0] = f2bs(x.x); va[1] = f2bs(x.y); va[2] = f2bs(x.z); va[3] = f2bs(x.w);
          va[4] = f2bs(y.x); va[5] = f2bs(y.y); va[6] = f2bs(y.z); va[7] = f2bs(y.w);
        } else {  // already bf16
          va = *reinterpret_cast<const short8*>((const short*)A + (size_t)gm * K + k0 + sc);
        }
      }
      *reinterpret_cast<short8*>(&As[r][sc]) = va;
      // B: weights, always bf16, always in-bounds (N % 128 == 0)
      *reinterpret_cast<short8*>(&Bs[r][sc]) =
          *reinterpret_cast<const short8*>(B + (size_t)(col0 + r) * K + k0 + sc);
    }
    __syncthreads();

    bf16x8 af[4], bfv[4];
#pragma unroll
    for (int i = 0; i < 4; i++) af[i]  = ldfrag(&As[wy * 64 + i * 16 + l16][quad * 8]);
#pragma unroll
    for (int i = 0; i < 4; i++) bfv[i] = ldfrag(&Bs[wx * 64 + i * 16 + l16][quad * 8]);
#pragma unroll
    for (int mi = 0; mi < 4; mi++)
#pragma unroll
      for (int ni = 0; ni < 4; ni++)
        acc[mi][ni] = __builtin_amdgcn_mfma_f32_16x16x32_bf16(af[mi], bfv[ni], acc[mi][ni], 0, 0, 0);
    __syncthreads();
  }

  // Epilogue: D[row=quad*4+r][col=l16] per 16x16 frag (m89-verified layout)
#pragma unroll
  for (int mi = 0; mi < 4; mi++) {
#pragma unroll
    for (int r = 0; r < 4; r++) {
      const int row = row0 + wy * 64 + mi * 16 + quad * 4 + r;
      if (row >= M) continue;
#pragma unroll
      for (int ni = 0; ni < 4; ni++) {
        const int col = col0 + wx * 64 + ni * 16 + l16;
        float v = acc[mi][ni][r];
        if constexpr (BIAS) v += bias[col];
        if constexpr (sizeof(OT) == 4)
          C[(size_t)row * N + col] = v;
        else
          C[(size_t)row * N + col] = f2bs(v);
      }
    }
  }
}

// ---------------------------------------------------------------------------
// Fused attention: per block = (b, h, 64 q rows); 4 waves x 16 rows each.
// Q read as A-frags from global bf16; K as B-frags from global bf16 (rows
// padded to 1240 so t=77..79 reads are in-bounds garbage, softmax-masked).
// V^T staged in LDS (cols 77..95 zeroed). Softmax in-register via shfl_xor
// over 16-lane quad groups. P -> per-wave LDS -> A-layout (m120 pattern).
// Output overwrites the Q buffer in place (disjoint rows/cols per wave).
// ---------------------------------------------------------------------------
__global__ __launch_bounds__(256)
void attn_kernel(const short* __restrict__ Kp, const short* __restrict__ Vp,
                 short* __restrict__ Qb) {
  __shared__ short Vt[160][104];      // V^T: [d][t], padded
  __shared__ short Pl[4][16][104];    // per-wave P

  const int tid  = threadIdx.x;
  const int b = blockIdx.z, h = blockIdx.y, s0 = blockIdx.x * 64;
  const int wave = tid >> 6, lane = tid & 63;
  const int quad = lane >> 4, l16 = lane & 15;

  // stage V^T (77x160 valid)
  for (int idx = tid; idx < 77 * 160; idx += 256) {
    int t = idx / 160, i = idx - t * 160;
    Vt[i][t] = Vp[((size_t)(b * 77 + t)) * 1280 + h * 160 + i];
  }
  // zero pad t = 77..95
  for (int idx = tid; idx < 160 * 19; idx += 256) {
    int i = idx / 19, t = 77 + (idx - i * 19);
    Vt[i][t] = 0;
  }
  __syncthreads();

  // Q fragments: A-layout, row = l16, k = kc*32 + quad*8 + j
  const short* Qg = Qb + ((size_t)b * 4096 + s0 + wave * 16 + l16) * 1280 + h * 160;
  bf16x8 qf[5];
#pragma unroll
  for (int kc = 0; kc < 5; kc++) qf[kc] = ldfrag(Qg + kc * 32 + quad * 8);

  // scores: S[16 x 80] per wave (5 n-tiles)
  f32x4 scv[5];
#pragma unroll
  for (int nt = 0; nt < 5; nt++) {
    f32x4 s = {};
    const short* Kg = Kp + ((size_t)(b * 77) + nt * 16 + l16) * 1280 + h * 160;
#pragma unroll
    for (int kc = 0; kc < 5; kc++) {
      bf16x8 kf = ldfrag(Kg + kc * 32 + quad * 8);
      s = __builtin_amdgcn_mfma_f32_16x16x32_bf16(qf[kc], kf, s, 0, 0, 0);
    }
    scv[nt] = s;
  }

  const float scale = 0.07905694150420949f;  // 160^-0.5
#pragma unroll
  for (int r = 0; r < 4; r++) {
    float v[5];
    float m = -1e30f;
#pragma unroll
    for (int nt = 0; nt < 5; nt++) {
      v[nt] = scv[nt][r];
      if (nt * 16 + l16 < 77) m = fmaxf(m, v[nt]);
    }
#pragma unroll
    for (int off = 1; off < 16; off <<= 1) m = fmaxf(m, __shfl_xor(m, off));
    float sum = 0.f, p[5];
#pragma unroll
    for (int nt = 0; nt < 5; nt++) {
      p[nt] = (nt * 16 + l16 < 77) ? __expf((v[nt] - m) * scale) : 0.f;
      sum += p[nt];
    }
#pragma unroll
    for (int off = 1; off < 16; off <<= 1) sum += __shfl_xor(sum, off);
    const float inv = 1.f / sum;
    const int q = quad * 4 + r;
#pragma unroll
    for (int nt = 0; nt < 5; nt++) Pl[wave][q][nt * 16 + l16] = f2bs(p[nt] * inv);
    Pl[wave][q][80 + l16] = 0;  // zero k = 80..95 pad
  }
  __syncthreads();  // conservative: guarantees P visible before ds_read frags

  // PV: P (A-layout from LDS) x V^T (B-frags from LDS), K-dim padded to 96
  bf16x8 pf[3];
#pragma unroll
  for (int kc = 0; kc < 3; kc++) pf[kc] = ldfrag(&Pl[wave][l16][kc * 32 + quad * 8]);

  short* Og = Qb + ((size_t)b * 4096 + s0 + wave * 16) * 1280 + h * 160;
#pragma unroll
  for (int nt = 0; nt < 10; nt++) {
    f32x4 o = {};
#pragma unroll
    for (int kc = 0; kc < 3; kc++) {
      bf16x8 vf = ldfrag(&Vt[nt * 16 + l16][kc * 32 + quad * 8]);
      o = __builtin_amdgcn_mfma_f32_16x16x32_bf16(pf[kc], vf, o, 0, 0, 0);
    }
#pragma unroll
    for (int r = 0; r < 4; r++) {
      const int q = quad * 4 + r;
      Og[(size_t)q * 1280 + nt * 16 + l16] = f2bs(o[r]);
    }
  }
}

// ---------------------------------------------------------------------------
extern "C" void kernel_launch(void* const* d_in, const int* in_sizes, int n_in,
                              void* d_out, int out_size, void* d_ws, size_t ws_size,
                              hipStream_t stream) {
  const float* hs  = (const float*)d_in[0];  // [16,4096,1280]
  const float* enc = (const float*)d_in[1];  // [16,77,768]
  const float* wq  = (const float*)d_in[2];  // [1280,1280]
  const float* wk  = (const float*)d_in[3];  // [1280,768]
  const float* wv  = (const float*)d_in[4];  // [1280,768]
  const float* wo  = (const float*)d_in[5];  // [1280,1280]
  const float* bo  = (const float*)d_in[6];  // [1280]
  float* out = (float*)d_out;

  // ws layout (bytes, all 256-aligned)
  char* ws = (char*)d_ws;
  short* wq_bf = (short*)(ws + 0);          // 1,638,400 el
  short* wk_bf = (short*)(ws + 3276800);    //   983,040 el
  short* wv_bf = (short*)(ws + 5242880);    //   983,040 el
  short* wo_bf = (short*)(ws + 7208960);    // 1,638,400 el
  short* Kp    = (short*)(ws + 10485760);   // 1240 x 1280 (rows 1232+ = masked pad)
  short* Vp    = (short*)(ws + 13660160);   // 1240 x 1280
  short* Qb    = (short*)(ws + 16834560);   // 65536 x 1280 (Q, then attn out in place)
  if (ws_size < (size_t)184606720) return;  // need ~185 MB

  cast_f32_bf16<<<1600, 256, 0, stream>>>(wq, wq_bf, 1638400);
  cast_f32_bf16<<<960,  256, 0, stream>>>(wk, wk_bf, 983040);
  cast_f32_bf16<<<960,  256, 0, stream>>>(wv, wv_bf, 983040);
  cast_f32_bf16<<<1600, 256, 0, stream>>>(wo, wo_bf, 1638400);

  // K/V projections: [1232,768] @ [1280,768]^T -> bf16 [1232,1280]
  dim3 g_kv(10, 10);
  gemm_bt<float, short, false><<<g_kv, 256, 0, stream>>>(enc, wk_bf, nullptr, Kp, 1232, 1280, 768);
  gemm_bt<float, short, false><<<g_kv, 256, 0, stream>>>(enc, wv_bf, nullptr, Vp, 1232, 1280, 768);

  // Q projection: [65536,1280] @ [1280,1280]^T -> bf16
  dim3 g_q(10, 512);
  gemm_bt<float, short, false><<<g_q, 256, 0, stream>>>(hs, wq_bf, nullptr, Qb, 65536, 1280, 1280);

  // fused attention (writes attn output over Qb in place)
  dim3 g_a(64, 8, 16);
  attn_kernel<<<g_a, 256, 0, stream>>>(Kp, Vp, Qb);

  // out projection + bias: [65536,1280] @ [1280,1280]^T + b -> fp32 d_out
  gemm_bt<short, float, true><<<g_q, 256, 0, stream>>>(Qb, wo_bf, bo, out, 65536, 1280, 1280);
}

// Round 2
// 1533.505 us; speedup vs baseline: 1.1283x; 1.1283x over previous
//
#include <hip/hip_runtime.h>
#include <hip/hip_bf16.h>

typedef __bf16 bf16x8 __attribute__((ext_vector_type(8)));
typedef short  short8 __attribute__((ext_vector_type(8)));
typedef float  f32x4  __attribute__((ext_vector_type(4)));

__device__ __forceinline__ short f2bs(float f) {
  return __builtin_bit_cast(short, __float2bfloat16(f));
}

__device__ __forceinline__ bf16x8 ldfrag(const short* p) {
  return *reinterpret_cast<const bf16x8*>(p);
}

// async global->LDS, 16B per lane. lds base must be wave-uniform; HW writes
// base + lane*16 (m104/m108). gaddr is per-lane.
__device__ __forceinline__ void gl2lds16(const short* g, short* lds_base) {
  __builtin_amdgcn_global_load_lds(
      (const __attribute__((address_space(1))) unsigned int*)g,
      (__attribute__((address_space(3))) unsigned int*)lds_base, 16, 0, 0);
}

// ---------------------------------------------------------------------------
// fp32 -> bf16 cast, 8 elements/thread, n % 8 == 0
// ---------------------------------------------------------------------------
__global__ __launch_bounds__(256) void cast8_f32_bf16(const float* __restrict__ in,
                                                      short* __restrict__ out, long n) {
  long i = ((long)blockIdx.x * 256 + threadIdx.x) * 8;
  if (i < n) {
    float4 a = *reinterpret_cast<const float4*>(in + i);
    float4 b = *reinterpret_cast<const float4*>(in + i + 4);
    short8 v;
    v[0] = f2bs(a.x); v[1] = f2bs(a.y); v[2] = f2bs(a.z); v[3] = f2bs(a.w);
    v[4] = f2bs(b.x); v[5] = f2bs(b.y); v[6] = f2bs(b.z); v[7] = f2bs(b.w);
    *reinterpret_cast<short8*>(out + i) = v;
  }
}

// ---------------------------------------------------------------------------
// m97-style GEMM: C[M,N] = A[M,K](bf16) @ B[N,K](bf16)^T (+bias)
// 128x128x32 tile, 256 thr = 4 waves (2x2), global_load_lds width-16 staging,
// unpadded 128x32 LDS tiles (layout must match lane order - no padding).
// Requires M,N % 128 == 0, K % 32 == 0.
// ---------------------------------------------------------------------------
template <typename OT, bool BIAS>
__global__ __launch_bounds__(256)
void gemm_fast(const short* __restrict__ A, const short* __restrict__ B,
               const float* __restrict__ bias, OT* __restrict__ C,
               int M, int N, int K) {
  __shared__ short As[128 * 32];
  __shared__ short Bs[128 * 32];

  const int tid  = threadIdx.x;
  const int wave = tid >> 6, lane = tid & 63;
  const int quad = lane >> 4, l16 = lane & 15;
  const int wy = wave >> 1, wx = wave & 1;
  const size_t row0 = (size_t)blockIdx.y * 128, col0 = (size_t)blockIdx.x * 128;

  const int srow = lane >> 2;        // 0..15 within 16-row segment
  const int scol = (lane & 3) * 8;   // 0,8,16,24 shorts

  // each wave stages rows [wave*32, wave*32+32) of both tiles (2 segs each)
  const short* Ab0 = A + (row0 + wave * 32 + srow) * (size_t)K + scol;
  const short* Ab1 = Ab0 + (size_t)16 * K;
  const short* Bb0 = B + (col0 + wave * 32 + srow) * (size_t)K + scol;
  const short* Bb1 = Bb0 + (size_t)16 * K;
  short* const Al0 = &As[(wave * 32) * 32];
  short* const Al1 = &As[(wave * 32 + 16) * 32];
  short* const Bl0 = &Bs[(wave * 32) * 32];
  short* const Bl1 = &Bs[(wave * 32 + 16) * 32];

  f32x4 acc[4][4] = {};

  for (int k0 = 0; k0 < K; k0 += 32) {
    gl2lds16(Ab0 + k0, Al0);
    gl2lds16(Ab1 + k0, Al1);
    gl2lds16(Bb0 + k0, Bl0);
    gl2lds16(Bb1 + k0, Bl1);
    __syncthreads();

    bf16x8 af[4], bv[4];
#pragma unroll
    for (int i = 0; i < 4; i++) af[i] = ldfrag(&As[(wy * 64 + i * 16 + l16) * 32 + quad * 8]);
#pragma unroll
    for (int i = 0; i < 4; i++) bv[i] = ldfrag(&Bs[(wx * 64 + i * 16 + l16) * 32 + quad * 8]);
#pragma unroll
    for (int mi = 0; mi < 4; mi++)
#pragma unroll
      for (int ni = 0; ni < 4; ni++)
        acc[mi][ni] = __builtin_amdgcn_mfma_f32_16x16x32_bf16(af[mi], bv[ni], acc[mi][ni], 0, 0, 0);
    __syncthreads();
  }

  // D layout per 16x16 frag: row = quad*4 + r, col = l16 (m89-verified)
#pragma unroll
  for (int mi = 0; mi < 4; mi++) {
#pragma unroll
    for (int r = 0; r < 4; r++) {
      const size_t row = row0 + wy * 64 + mi * 16 + quad * 4 + r;
#pragma unroll
      for (int ni = 0; ni < 4; ni++) {
        const size_t col = col0 + wx * 64 + ni * 16 + l16;
        float v = acc[mi][ni][r];
        if constexpr (BIAS) v += bias[col];
        if constexpr (sizeof(OT) == 4)
          C[row * N + col] = v;
        else
          C[row * N + col] = f2bs(v);
      }
    }
  }
}

// ---------------------------------------------------------------------------
// Small guarded GEMM (KV projections only): C = A(fp32) @ B(bf16)^T -> bf16.
// Same as Round-1 kernel; M guarded, inline fp32->bf16 in staging.
// ---------------------------------------------------------------------------
__global__ __launch_bounds__(256)
void gemm_small(const float* __restrict__ A, const short* __restrict__ B,
                short* __restrict__ C, int M, int N, int K) {
  __shared__ short As[128][40];
  __shared__ short Bs[128][40];

  const int tid  = threadIdx.x;
  const int wave = tid >> 6, lane = tid & 63;
  const int quad = lane >> 4, l16 = lane & 15;
  const int wy = wave >> 1, wx = wave & 1;
  const int row0 = blockIdx.y * 128, col0 = blockIdx.x * 128;
  const int sr = tid >> 2;
  const int sc = (tid & 3) * 8;

  f32x4 acc[4][4] = {};

  for (int k0 = 0; k0 < K; k0 += 32) {
    for (int p = 0; p < 128; p += 64) {
      const int r  = sr + p;
      const int gm = row0 + r;
      short8 va = {0, 0, 0, 0, 0, 0, 0, 0};
      if (gm < M) {
        const float* ap = A + (size_t)gm * K + k0 + sc;
        float4 x = *reinterpret_cast<const float4*>(ap);
        float4 y = *reinterpret_cast<const float4*>(ap + 4);
        va[0] = f2bs(x.x); va[1] = f2bs(x.y); va[2] = f2bs(x.z); va[3] = f2bs(x.w);
        va[4] = f2bs(y.x); va[5] = f2bs(y.y); va[6] = f2bs(y.z); va[7] = f2bs(y.w);
      }
      *reinterpret_cast<short8*>(&As[r][sc]) = va;
      *reinterpret_cast<short8*>(&Bs[r][sc]) =
          *reinterpret_cast<const short8*>(B + (size_t)(col0 + r) * K + k0 + sc);
    }
    __syncthreads();

    bf16x8 af[4], bv[4];
#pragma unroll
    for (int i = 0; i < 4; i++) af[i] = ldfrag(&As[wy * 64 + i * 16 + l16][quad * 8]);
#pragma unroll
    for (int i = 0; i < 4; i++) bv[i] = ldfrag(&Bs[wx * 64 + i * 16 + l16][quad * 8]);
#pragma unroll
    for (int mi = 0; mi < 4; mi++)
#pragma unroll
      for (int ni = 0; ni < 4; ni++)
        acc[mi][ni] = __builtin_amdgcn_mfma_f32_16x16x32_bf16(af[mi], bv[ni], acc[mi][ni], 0, 0, 0);
    __syncthreads();
  }

#pragma unroll
  for (int mi = 0; mi < 4; mi++) {
#pragma unroll
    for (int r = 0; r < 4; r++) {
      const int row = row0 + wy * 64 + mi * 16 + quad * 4 + r;
      if (row >= M) continue;
#pragma unroll
      for (int ni = 0; ni < 4; ni++) {
        const int col = col0 + wx * 64 + ni * 16 + l16;
        C[(size_t)row * N + col] = f2bs(acc[mi][ni][r]);
      }
    }
  }
}

// ---------------------------------------------------------------------------
// Fused attention: block = (b, h, 64 q rows); 4 waves x 16 rows.
// Q read as A-frags from global bf16 Qin; K as B-frags (rows padded to 1240,
// t>=77 garbage masked). V^T staged in LDS. Softmax in-register (shfl_xor over
// 16-lane groups). P -> per-wave LDS -> A-layout. O written to Oout.
// ---------------------------------------------------------------------------
__global__ __launch_bounds__(256)
void attn_kernel(const short* __restrict__ Kp, const short* __restrict__ Vp,
                 const short* __restrict__ Qin, short* __restrict__ Oout) {
  __shared__ short Vt[160][104];
  __shared__ short Pl[4][16][104];

  const int tid  = threadIdx.x;
  const int b = blockIdx.z, h = blockIdx.y, s0 = blockIdx.x * 64;
  const int wave = tid >> 6, lane = tid & 63;
  const int quad = lane >> 4, l16 = lane & 15;

  for (int idx = tid; idx < 77 * 160; idx += 256) {
    int t = idx / 160, i = idx - t * 160;
    Vt[i][t] = Vp[((size_t)(b * 77 + t)) * 1280 + h * 160 + i];
  }
  for (int idx = tid; idx < 160 * 19; idx += 256) {
    int i = idx / 19, t = 77 + (idx - i * 19);
    Vt[i][t] = 0;
  }
  __syncthreads();

  const short* Qg = Qin + ((size_t)b * 4096 + s0 + wave * 16 + l16) * 1280 + h * 160;
  bf16x8 qf[5];
#pragma unroll
  for (int kc = 0; kc < 5; kc++) qf[kc] = ldfrag(Qg + kc * 32 + quad * 8);

  f32x4 scv[5];
#pragma unroll
  for (int nt = 0; nt < 5; nt++) {
    f32x4 s = {};
    const short* Kg = Kp + ((size_t)(b * 77) + nt * 16 + l16) * 1280 + h * 160;
#pragma unroll
    for (int kc = 0; kc < 5; kc++) {
      bf16x8 kf = ldfrag(Kg + kc * 32 + quad * 8);
      s = __builtin_amdgcn_mfma_f32_16x16x32_bf16(qf[kc], kf, s, 0, 0, 0);
    }
    scv[nt] = s;
  }

  const float scale = 0.07905694150420949f;  // 160^-0.5
#pragma unroll
  for (int r = 0; r < 4; r++) {
    float v[5];
    float m = -1e30f;
#pragma unroll
    for (int nt = 0; nt < 5; nt++) {
      v[nt] = scv[nt][r];
      if (nt * 16 + l16 < 77) m = fmaxf(m, v[nt]);
    }
#pragma unroll
    for (int off = 1; off < 16; off <<= 1) m = fmaxf(m, __shfl_xor(m, off));
    float sum = 0.f, p[5];
#pragma unroll
    for (int nt = 0; nt < 5; nt++) {
      p[nt] = (nt * 16 + l16 < 77) ? __expf((v[nt] - m) * scale) : 0.f;
      sum += p[nt];
    }
#pragma unroll
    for (int off = 1; off < 16; off <<= 1) sum += __shfl_xor(sum, off);
    const float inv = 1.f / sum;
    const int q = quad * 4 + r;
#pragma unroll
    for (int nt = 0; nt < 5; nt++) Pl[wave][q][nt * 16 + l16] = f2bs(p[nt] * inv);
    Pl[wave][q][80 + l16] = 0;
  }
  __syncthreads();

  bf16x8 pf[3];
#pragma unroll
  for (int kc = 0; kc < 3; kc++) pf[kc] = ldfrag(&Pl[wave][l16][kc * 32 + quad * 8]);

  short* Og = Oout + ((size_t)b * 4096 + s0 + wave * 16) * 1280 + h * 160;
#pragma unroll
  for (int nt = 0; nt < 10; nt++) {
    f32x4 o = {};
#pragma unroll
    for (int kc = 0; kc < 3; kc++) {
      bf16x8 vf = ldfrag(&Vt[nt * 16 + l16][kc * 32 + quad * 8]);
      o = __builtin_amdgcn_mfma_f32_16x16x32_bf16(pf[kc], vf, o, 0, 0, 0);
    }
#pragma unroll
    for (int r = 0; r < 4; r++) {
      const int q = quad * 4 + r;
      Og[(size_t)q * 1280 + nt * 16 + l16] = f2bs(o[r]);
    }
  }
}

// ---------------------------------------------------------------------------
extern "C" void kernel_launch(void* const* d_in, const int* in_sizes, int n_in,
                              void* d_out, int out_size, void* d_ws, size_t ws_size,
                              hipStream_t stream) {
  const float* hs  = (const float*)d_in[0];  // [16,4096,1280]
  const float* enc = (const float*)d_in[1];  // [16,77,768]
  const float* wq  = (const float*)d_in[2];
  const float* wk  = (const float*)d_in[3];
  const float* wv  = (const float*)d_in[4];
  const float* wo  = (const float*)d_in[5];
  const float* bo  = (const float*)d_in[6];
  float* out = (float*)d_out;

  // ws layout (bytes)
  char* ws = (char*)d_ws;
  short* wq_bf = (short*)(ws + 0);          // 1,638,400 el
  short* wk_bf = (short*)(ws + 3276800);    //   983,040 el
  short* wv_bf = (short*)(ws + 5242880);    //   983,040 el
  short* wo_bf = (short*)(ws + 7208960);    // 1,638,400 el
  short* Kp    = (short*)(ws + 10485760);   // 1240 x 1280 (rows >=1232 masked)
  short* Vp    = (short*)(ws + 13660160);   // 1240 x 1280
  short* Xbf   = (short*)(ws + 16834560);   // 65536 x 1280: hs_bf, later attn-out
  if (ws_size < (size_t)184606720) return;

  // bf16 Q buffer parked in d_out (335 MB fp32 >= 167.8 MB bf16; fully
  // overwritten by the final out-projection).
  short* Qb = (short*)d_out;

  cast8_f32_bf16<<<800, 256, 0, stream>>>(wq, wq_bf, 1638400);
  cast8_f32_bf16<<<480, 256, 0, stream>>>(wk, wk_bf, 983040);
  cast8_f32_bf16<<<480, 256, 0, stream>>>(wv, wv_bf, 983040);
  cast8_f32_bf16<<<800, 256, 0, stream>>>(wo, wo_bf, 1638400);
  cast8_f32_bf16<<<40960, 256, 0, stream>>>(hs, Xbf, 83886080);

  // K/V projections: [1232,768] @ [1280,768]^T -> bf16
  dim3 g_kv(10, 10);
  gemm_small<<<g_kv, 256, 0, stream>>>(enc, wk_bf, Kp, 1232, 1280, 768);
  gemm_small<<<g_kv, 256, 0, stream>>>(enc, wv_bf, Vp, 1232, 1280, 768);

  // Q projection: [65536,1280] @ [1280,1280]^T -> bf16 (into d_out scratch)
  dim3 g_q(10, 512);
  gemm_fast<short, false><<<g_q, 256, 0, stream>>>(Xbf, wq_bf, nullptr, Qb, 65536, 1280, 1280);

  // fused attention: reads Qb (d_out), writes O over Xbf (hs_bf is dead)
  dim3 g_a(64, 8, 16);
  attn_kernel<<<g_a, 256, 0, stream>>>(Kp, Vp, Qb, Xbf);

  // out projection + bias -> fp32 d_out
  gemm_fast<float, true><<<g_q, 256, 0, stream>>>(Xbf, wo_bf, bo, out, 65536, 1280, 1280);
}